// Round 6
// baseline (640.693 us; speedup 1.0000x reference)
//
#include <hip/hip_runtime.h>
#include <cstdint>
#include <cstddef>

// Problem constants (fixed by the reference)
#define NN   50000
#define MM   24
#define FNIN 92
#define FEIN 41
#define NBLK 3125            // NN / 16 nodes per conv block
#define EROW 48              // edge row padded 41 -> 48 bf16 (96 B)
#define ETILE (MM * 16 * EROW)  // 18432 elems per node-block tile
#define LOG2E 1.4426950408889634f
#define LN2   0.6931471805599453f

typedef __attribute__((ext_vector_type(8))) short bf16x8;
typedef __attribute__((ext_vector_type(4))) float f32x4;
typedef __attribute__((ext_vector_type(8))) unsigned short u16x8;
typedef __attribute__((ext_vector_type(2))) _Float16 f16x2;

__device__ __forceinline__ unsigned short f2bf(float x) {
    unsigned int u = __float_as_uint(x);
    return (unsigned short)((u + 0x7fffu + ((u >> 16) & 1u)) >> 16);  // RNE
}
__device__ __forceinline__ float bf2f(unsigned short h) {
    return __uint_as_float(((unsigned int)h) << 16);
}
__device__ __forceinline__ _Float16 f2h_clamp(float x) {
    return (_Float16)fminf(fmaxf(x, -60000.f), 60000.f);   // stay finite in fp16
}
__device__ __forceinline__ float exp2f_fast(float x) {
#if __has_builtin(__builtin_amdgcn_exp2f)
    return __builtin_amdgcn_exp2f(x);
#else
    float r; asm("v_exp_f32 %0, %1" : "=v"(r) : "v"(x)); return r;
#endif
}
__device__ __forceinline__ float log2f_fast(float x) {
#if __has_builtin(__builtin_amdgcn_logf)
    return __builtin_amdgcn_logf(x);
#else
    float r; asm("v_log_f32 %0, %1" : "=v"(r) : "v"(x)); return r;
#endif
}

// GATE PRE-SCALING: all inputs to the gated sum (WcB, WsnB -> Ps/Pn, bias_c)
// are multiplied by log2e at prep time, so conv computes gf' = gf*log2e and
// can use native exp2/log2 with no range-reduction muls:
//   sigmoid(gf)  = rcp(1 + exp2(-gf'))
//   softplus(gc) = ln2 * (max(gc',0) + log2(1 + exp2(-|gc'|)))   (ln2 deferred)
// Pn sentinel row at node==NN: filter=-60000 (exp2 overflows -> sigmoid=+0),
// core=0 -> padded neighbors contribute exactly 0; no mask ops in the loop.

// ---------------------------------------------------------------------------
// prep: build per-layer combined weights in MFMA B-fragment order + Pn sentinel.
//   WcB_l : B[k][n] = log2e*(We @ W_l[128:192])[k][n], k<41 else 0.
//   WsnBhi/lo_l: split-bf16 of log2e*W_l[k][n] (n<128 -> Ps) /
//                log2e*W_l[64+k][n-128] (-> Pn).
//   bias_c_l[n] = log2e*(b_l[n] + (be @ W_l[128:192])[n])
// W[128:192] and We staged in LDS (removes 65k strided global reads/block).
// Fragment elem layout: idx = ((j*2+s)*64 + lane)*8 + t ; k = s*32 + (lane>>4)*8 + t ;
//                       n = 16*j + (lane&15)
// ---------------------------------------------------------------------------
__global__ __launch_bounds__(256) void prep_kernel(
    const float* __restrict__ We, const float* __restrict__ be,
    const float* __restrict__ W1, const float* __restrict__ b1,
    const float* __restrict__ W2, const float* __restrict__ b2,
    const float* __restrict__ W3, const float* __restrict__ b3,
    unsigned short* __restrict__ WcB,
    unsigned short* __restrict__ WsnBhi, unsigned short* __restrict__ WsnBlo,
    float* __restrict__ bias_c, _Float16* __restrict__ Pn)
{
    __shared__ float Wu_s[64 * 128];     // W rows 128..191 (32 KB)
    __shared__ float We_s[FEIN * 64];    // 10.5 KB
    int l = blockIdx.x / 24;
    int part = blockIdx.x % 24;
    const float* W  = (l == 0) ? W1 : (l == 1) ? W2 : W3;
    const float* bl = (l == 0) ? b1 : (l == 1) ? b2 : b3;
    int tid = threadIdx.x;
    if (blockIdx.x == 0 && tid < 128) {
        // sentinel row: filter (even) = -60000, core (odd) = 0  (NOT scaled; any
        // very-negative filter value works -- exp2(+6e4)=inf -> rcp=0)
        Pn[(size_t)NN * 128 + tid] = (tid & 1) ? (_Float16)0.f : (_Float16)(-60000.f);
    }
    if (part < 8) {
        for (int i = tid; i < 64 * 128; i += 256) Wu_s[i] = W[128 * 128 + i];
        for (int i = tid; i < FEIN * 64; i += 256) We_s[i] = We[i];
        __syncthreads();
        int j = part;
        for (int e = tid; e < 1024; e += 256) {
            int s = e >> 9, L = (e >> 3) & 63, t = e & 7;
            int k = s * 32 + ((L >> 4) << 3) + t;
            int n = 16 * j + (L & 15);
            float v = 0.f;
            if (k < FEIN) {
                for (int i = 0; i < 64; ++i)
                    v += We_s[k * 64 + i] * Wu_s[i * 128 + n];
            }
            WcB[l * 8192 + j * 1024 + e] = f2bf(v * LOG2E);
        }
        if (part == 0 && tid < 128) {
            float v = bl[tid];
            for (int i = 0; i < 64; ++i)
                v += be[i] * Wu_s[i * 128 + tid];
            bias_c[l * 128 + tid] = v * LOG2E;
        }
    } else {
        int j = part - 8;
        for (int e = tid; e < 1024; e += 256) {
            int s = e >> 9, L = (e >> 3) & 63, t = e & 7;
            int k = s * 32 + ((L >> 4) << 3) + t;
            int n = 16 * j + (L & 15);
            float v = (n < 128) ? W[k * 128 + n] : W[(64 + k) * 128 + (n - 128)];
            v *= LOG2E;
            unsigned short h = f2bf(v);
            WsnBhi[l * 16384 + j * 1024 + e] = h;
            WsnBlo[l * 16384 + j * 1024 + e] = f2bf(v - bf2f(h));
        }
    }
}

// ---------------------------------------------------------------------------
// cast: edge_fea (N,M,41) fp32 -> block-tiled bf16, m-major rows, k padded
// to 48. 8 nodes per block: coalesced float4 read -> LDS -> transposed ushort8
// (16 B) stores.
// ---------------------------------------------------------------------------
#define CN 8                      // nodes per cast block
__global__ __launch_bounds__(256) void cast_kernel(
    const float* __restrict__ edge_fea, unsigned short* __restrict__ edge_tiles)
{
    __shared__ float s[CN * MM * FEIN];   // 7872 floats = 31.5 KB
    int B = blockIdx.x;
    int b = B >> 1, half = B & 1;
    const float4* src = (const float4*)(edge_fea + ((size_t)b * 16 + half * CN) * (MM * FEIN));
    float4* sd = (float4*)s;
    for (int i = threadIdx.x; i < (CN * MM * FEIN) / 4; i += 256)
        sd[i] = src[i];
    __syncthreads();
    unsigned short* dst = edge_tiles + (size_t)b * ETILE;
    for (int c = threadIdx.x; c < CN * MM * 6; c += 256) {   // 6 chunks of 8 per row
        int r = c / 6, cc = c - r * 6;
        int m = r >> 3, nbl = r & 7;          // 192 rows: m-major over 8 local nodes
        int k0 = cc * 8;
        const float* srow = &s[(nbl * MM + m) * FEIN];
        u16x8 v;
        #pragma unroll
        for (int j = 0; j < 8; ++j) {
            int k = k0 + j;
            v[j] = (k < FEIN) ? f2bf(srow[k]) : (unsigned short)0;
        }
        *(u16x8*)(dst + (size_t)(m * 16 + half * CN + nbl) * EROW + k0) = v;
    }
}

// ---------------------------------------------------------------------------
// embed: node0 = node_fea @ Wn + bn   (50000x92 @ 92x64), fp32 VALU (exact).
// ---------------------------------------------------------------------------
__global__ __launch_bounds__(256) void embed_kernel(
    const float* __restrict__ node_fea, const float* __restrict__ Wn,
    const float* __restrict__ bn, float* __restrict__ node_out)
{
    __shared__ float w_s[FNIN * 64];
    __shared__ float f_s[64 * FNIN];
    int tid = threadIdx.x;
    int base = blockIdx.x * 64;
    int cnt = min(64, NN - base);
    for (int i = tid; i < FNIN * 64; i += 256) w_s[i] = Wn[i];
    for (int i = tid; i < cnt * FNIN; i += 256) f_s[i] = node_fea[base * FNIN + i];
    __syncthreads();
    int c = tid & 63, g = tid >> 6;
    float acc[16];
    #pragma unroll
    for (int jj = 0; jj < 16; ++jj) acc[jj] = 0.f;
    for (int k = 0; k < FNIN; ++k) {
        float wv = w_s[k * 64 + c];               // conflict-free
        #pragma unroll
        for (int jj = 0; jj < 16; ++jj)
            acc[jj] += f_s[(g + 4 * jj) * FNIN + k] * wv;   // wave-broadcast
    }
    float bv = bn[c];
    #pragma unroll
    for (int jj = 0; jj < 16; ++jj) {
        int n = g + 4 * jj;
        if (n < cnt) node_out[(base + n) * 64 + c] = acc[jj] + bv;
    }
}

// ---------------------------------------------------------------------------
// p: P = node @ [W_s | W_n] -> Ps (N x 128 fp16), Pn (N x 128 fp16), both in
// pair-interleaved layout (filter/core adjacent), written as f16x2 (4 B).
// Split-bf16 MFMA; values are log2e-scaled via WsnB. fp16 storage ~0.05% rel err.
// ---------------------------------------------------------------------------
__global__ __launch_bounds__(256) void p_kernel(
    const float* __restrict__ node,
    const unsigned short* __restrict__ Bhi, const unsigned short* __restrict__ Blo,
    _Float16* __restrict__ Ps, _Float16* __restrict__ Pn)
{
    __shared__ float n_s[64 * 68];          // stride 68 floats: 2-way LDS aliasing only
    int tid = threadIdx.x;
    int base = blockIdx.x * 64;
    int cnt = min(64, NN - base);
    for (int i = tid; i < cnt * 64; i += 256) {
        int r = i >> 6, c = i & 63;
        n_s[r * 68 + c] = node[base * 64 + i];
    }
    __syncthreads();
    int w = tid >> 6, L = tid & 63, quad = L >> 4, lc = L & 15;
    const float* ap = &n_s[(16 * w + lc) * 68 + quad * 8];
    bf16x8 a0h, a0l, a1h, a1l;
    for (int t = 0; t < 8; ++t) {
        float x0 = ap[t];                   // k = quad*8 + t
        float x1 = ap[32 + t];              // k = 32 + quad*8 + t
        unsigned short h0 = f2bf(x0), h1 = f2bf(x1);
        a0h[t] = (short)h0; a1h[t] = (short)h1;
        a0l[t] = (short)f2bf(x0 - bf2f(h0));
        a1l[t] = (short)f2bf(x1 - bf2f(h1));
    }
    const bf16x8* bh = (const bf16x8*)Bhi;
    const bf16x8* bl = (const bf16x8*)Blo;
    #pragma unroll
    for (int jp = 0; jp < 8; ++jp) {
        int jf = (jp < 4) ? jp : (jp + 4);       // filter tile
        int jc = jf + 4;                         // core tile
        bf16x8 f0h = bh[(jf * 2 + 0) * 64 + L];
        bf16x8 f1h = bh[(jf * 2 + 1) * 64 + L];
        bf16x8 f0l = bl[(jf * 2 + 0) * 64 + L];
        bf16x8 f1l = bl[(jf * 2 + 1) * 64 + L];
        bf16x8 c0h = bh[(jc * 2 + 0) * 64 + L];
        bf16x8 c1h = bh[(jc * 2 + 1) * 64 + L];
        bf16x8 c0l = bl[(jc * 2 + 0) * 64 + L];
        bf16x8 c1l = bl[(jc * 2 + 1) * 64 + L];
        f32x4 Cf = {0.f, 0.f, 0.f, 0.f}, Cc = {0.f, 0.f, 0.f, 0.f};
        Cf = __builtin_amdgcn_mfma_f32_16x16x32_bf16(a0h, f0h, Cf, 0, 0, 0);
        Cf = __builtin_amdgcn_mfma_f32_16x16x32_bf16(a1h, f1h, Cf, 0, 0, 0);
        Cf = __builtin_amdgcn_mfma_f32_16x16x32_bf16(a0l, f0h, Cf, 0, 0, 0);
        Cf = __builtin_amdgcn_mfma_f32_16x16x32_bf16(a1l, f1h, Cf, 0, 0, 0);
        Cf = __builtin_amdgcn_mfma_f32_16x16x32_bf16(a0h, f0l, Cf, 0, 0, 0);
        Cf = __builtin_amdgcn_mfma_f32_16x16x32_bf16(a1h, f1l, Cf, 0, 0, 0);
        Cc = __builtin_amdgcn_mfma_f32_16x16x32_bf16(a0h, c0h, Cc, 0, 0, 0);
        Cc = __builtin_amdgcn_mfma_f32_16x16x32_bf16(a1h, c1h, Cc, 0, 0, 0);
        Cc = __builtin_amdgcn_mfma_f32_16x16x32_bf16(a0l, c0h, Cc, 0, 0, 0);
        Cc = __builtin_amdgcn_mfma_f32_16x16x32_bf16(a1l, c1h, Cc, 0, 0, 0);
        Cc = __builtin_amdgcn_mfma_f32_16x16x32_bf16(a0h, c0l, Cc, 0, 0, 0);
        Cc = __builtin_amdgcn_mfma_f32_16x16x32_bf16(a1h, c1l, Cc, 0, 0, 0);
        int cl = (jp < 4) ? (16 * jp + lc) : (16 * (jp - 4) + lc);   // col in [0,64)
        _Float16* P = (jp < 4) ? Ps : Pn;
        #pragma unroll
        for (int r = 0; r < 4; ++r) {
            int nr = 16 * w + quad * 4 + r;  // C layout: row = quad*4 + reg
            if (nr < cnt) {
                f16x2 v = {f2h_clamp(Cf[r]), f2h_clamp(Cc[r])};
                *(f16x2*)&P[(size_t)(base + nr) * 128 + 2 * cl] = v;
            }
        }
    }
}

// ---------------------------------------------------------------------------
// conv: one layer. Block = 16 nodes. Mod-4 register-set software pipeline:
// sets (pn, edge-frag, offset) keyed by m%4; two alternating inline bodies
// (even/odd iteration) -> zero rotate movs. Depths:
//   gather VALUES + edge frags: depth-2 ITERATIONS (4 m-steps ~1000 own-cy,
//                               covers HBM ~900cy / L3 ~600cy)
//   gather OFFSETS: read 2 iterations before their VAL use (covers lgkm)
// ofs table sentinel-padded to stride 32 (slots 24..31) -> no clamps on the
// offset/VAL path; EDG clamped to the in-bounds m=24 pad row.
// (Full 24x unroll REGRESSED earlier: 176 VGPR / 10% occupancy -> keep the
// dynamic outer loop, #pragma unroll 1.)
// Per m: C_edge = edge_m @ Wc (2 MFMA ksteps; K-pad zeros in B); C init = psb
// (Ps[self]+bias, log2e-scaled); gated = C + Pn[idx];
// acc += rcp(1+exp2(-gf)) * (max(gc,0)+log2(1+exp2(-|gc|)));  *ln2 deferred.
// ---------------------------------------------------------------------------
__global__ __launch_bounds__(256, 4) void conv_kernel(
    const float* __restrict__ node_in, const int* __restrict__ idx,
    const unsigned short* __restrict__ edge_tiles,
    const _Float16* __restrict__ Ps, const _Float16* __restrict__ Pn,
    const unsigned short* __restrict__ WcB, const float* __restrict__ bias_c,
    const float* __restrict__ alpha_p, float* __restrict__ node_out)
{
    __shared__ unsigned ofs_s[16 * 32];     // (gg<<8); stride 32; slots 24..31 sentinel
    int tid = threadIdx.x;
    int b = blockIdx.x;
    int base = b * 16;
    for (int i = tid; i < 16 * 32; i += 256) {
        int row = i >> 5, m = i & 31;
        unsigned gg = (unsigned)NN;                    // sentinel row
        if (m < MM) {
            int g = idx[base * MM + row * MM + m];
            gg = (unsigned)((g >= 0) ? g : NN);
        }
        ofs_s[i] = gg << 8;                            // byte offset of Pn row
    }
    __syncthreads();

    int w = tid >> 6, L = tid & 63, quad = L >> 4, lc = L & 15;
    int colf = 16 * w + lc;                  // filter col (0..63) == output col
    const bf16x8* wcb = (const bf16x8*)WcB;
    bf16x8 bf0 = wcb[(w * 2 + 0) * 64 + L];        // filter tile j=w, kstep 0
    bf16x8 bf1 = wcb[(w * 2 + 1) * 64 + L];        // kstep 1 (k>=41 rows are zero)
    bf16x8 bc0 = wcb[((w + 4) * 2 + 0) * 64 + L];  // core tile j=w+4
    bf16x8 bc1 = wcb[((w + 4) * 2 + 1) * 64 + L];

    float bias_f = bias_c[colf];
    float bias_g = bias_c[64 + colf];
    float psb_f[4], psb_c[4];
    #pragma unroll
    for (int r = 0; r < 4; ++r) {
        int nr = base + quad * 4 + r;
        f16x2 sp = *(const f16x2*)&Ps[(size_t)nr * 128 + 2 * colf];
        psb_f[r] = (float)sp[0] + bias_f;
        psb_c[r] = (float)sp[1] + bias_g;
    }

    float acc[4] = {0.f, 0.f, 0.f, 0.f};
    const char* PnB = (const char*)Pn;
    unsigned coff = (unsigned)colf << 2;         // byte offset of f16x2 pair in a row
    const unsigned* ofsr = &ofs_s[quad * 4 * 32];   // rows quad*4..+3, stride 32
    // A-frag base: row = lc, chunk = quad (kstep1 may read past the 48-elem row
    // for quad>=2 -- finite garbage nullified by zero B rows k>=41).
    const unsigned short* et = edge_tiles + (size_t)b * ETILE + lc * EROW + quad * 8;

    auto conv_step = [&](const f16x2 (&PN)[4], bf16x8 A0, bf16x8 A1) {
        f32x4 Cf = {psb_f[0], psb_f[1], psb_f[2], psb_f[3]};
        f32x4 Cc = {psb_c[0], psb_c[1], psb_c[2], psb_c[3]};
        Cf = __builtin_amdgcn_mfma_f32_16x16x32_bf16(A0, bf0, Cf, 0, 0, 0);
        Cf = __builtin_amdgcn_mfma_f32_16x16x32_bf16(A1, bf1, Cf, 0, 0, 0);
        Cc = __builtin_amdgcn_mfma_f32_16x16x32_bf16(A0, bc0, Cc, 0, 0, 0);
        Cc = __builtin_amdgcn_mfma_f32_16x16x32_bf16(A1, bc1, Cc, 0, 0, 0);
        #pragma unroll
        for (int r = 0; r < 4; ++r) {
            float gf = Cf[r] + (float)PN[r][0];
            float gc = Cc[r] + (float)PN[r][1];
            float sg = __builtin_amdgcn_rcpf(1.0f + exp2f_fast(-gf));   // sentinel: rcp(inf)=+0
            float sp2 = fmaxf(gc, 0.f)
                      + log2f_fast(1.0f + exp2f_fast(fminf(gc, -gc)));  // -|gc| in 1 op
            acc[r] = fmaf(sg, sp2, acc[r]);
        }
    };
    auto val_load = [&](f16x2 (&PN)[4], const unsigned (&O)[4]) {
        #pragma unroll
        for (int r = 0; r < 4; ++r)
            PN[r] = *(const f16x2*)(PnB + (O[r] + coff));
    };
    auto edg_load = [&](bf16x8& A0, bf16x8& A1, int m) {
        const unsigned short* ep = et + m * 768;     // 16*EROW elems per m
        A0 = *(const bf16x8*)(ep);
        A1 = *(const bf16x8*)(ep + 32);
    };
    auto ofs_read = [&](unsigned (&O)[4], int slot) {
        #pragma unroll
        for (int r = 0; r < 4; ++r) O[r] = ofsr[r * 32 + slot];
    };

    // mod-4 register sets
    unsigned o0[4], o1[4], o2[4], o3[4];
    f16x2 pn0[4], pn1[4], pn2[4], pn3[4];
    bf16x8 a0_0, a0_1, a1_0, a1_1, a2_0, a2_1, a3_0, a3_1;

    // ---- prologue: offsets m=0..3; issue VAL/EDG m=0..3; offsets m=4,5 ----
    ofs_read(o0, 0); ofs_read(o1, 1); ofs_read(o2, 2); ofs_read(o3, 3);
    val_load(pn0, o0); val_load(pn1, o1); val_load(pn2, o2); val_load(pn3, o3);
    edg_load(a0_0, a0_1, 0); edg_load(a1_0, a1_1, 1);
    edg_load(a2_0, a2_1, 2); edg_load(a3_0, a3_1, 3);
    ofs_read(o0, 4); ofs_read(o1, 5);   // o2,o3 refilled by iter 0's OFS reads

    #pragma unroll 1
    for (int tt = 0; tt < 6; ++tt) {
        int m = 4 * tt;
        int mE = min(m + 4, 24), mO = min(m + 5, 24);   // 24 = in-bounds pad row
        // ---- even iter: compute m, m+1 (sets 0,1); refill sets 0,1 ----
        conv_step(pn0, a0_0, a0_1);
        val_load(pn0, o0);               // VAL(m+4)
        edg_load(a0_0, a0_1, mE);        // EDG(m+4)
        ofs_read(o2, m + 6);             // o(m+6) -> set 2
        conv_step(pn1, a1_0, a1_1);
        val_load(pn1, o1);               // VAL(m+5)
        edg_load(a1_0, a1_1, mO);        // EDG(m+5)
        ofs_read(o3, m + 7);             // o(m+7) -> set 3
        // ---- odd iter: compute m+2, m+3 (sets 2,3); refill sets 2,3 ----
        int mE2 = min(m + 6, 24), mO2 = min(m + 7, 24);
        conv_step(pn2, a2_0, a2_1);
        val_load(pn2, o2);               // VAL(m+6)
        edg_load(a2_0, a2_1, mE2);       // EDG(m+6)
        ofs_read(o0, m + 8);             // o(m+8) -> set 0
        conv_step(pn3, a3_0, a3_1);
        val_load(pn3, o3);               // VAL(m+7)
        edg_load(a3_0, a3_1, mO2);       // EDG(m+7)
        ofs_read(o1, m + 9);             // o(m+9) -> set 1
    }

    float alpha = alpha_p[0];
    #pragma unroll
    for (int r = 0; r < 4; ++r) {
        int nr = base + quad * 4 + r;
        float x = alpha * node_in[nr * 64 + colf] + acc[r] * LN2;   // back to ln domain
        float o = fmaxf(x, 0.f) + __logf(1.0f + __expf(-fabsf(x)));
        node_out[nr * 64 + colf] = o;
    }
}

// ---------------------------------------------------------------------------
extern "C" void kernel_launch(void* const* d_in, const int* in_sizes, int n_in,
                              void* d_out, int out_size, void* d_ws, size_t ws_size,
                              hipStream_t stream)
{
    const float* node_fea = (const float*)d_in[0];
    const float* edge_fea = (const float*)d_in[1];
    const int*   eidx     = (const int*)d_in[2];
    const float* Wn = (const float*)d_in[3];
    const float* bn = (const float*)d_in[4];
    const float* We = (const float*)d_in[5];
    const float* be = (const float*)d_in[6];
    const float* W1 = (const float*)d_in[7];
    const float* b1 = (const float*)d_in[8];
    const float* a1 = (const float*)d_in[9];
    const float* W2 = (const float*)d_in[10];
    const float* b2 = (const float*)d_in[11];
    const float* a2 = (const float*)d_in[12];
    const float* W3 = (const float*)d_in[13];
    const float* b3 = (const float*)d_in[14];
    const float* a3 = (const float*)d_in[15];
    float* out = (float*)d_out;

    // Workspace layout (~167 MiB total)
    char* ws = (char*)d_ws;
    unsigned short* edge_tiles = (unsigned short*)ws;   // 115,200,000 B + 4 KB pad
    size_t off = 115204352;                             // (conv prefetch over-read pad)
    float* nodeA = (float*)(ws + off); off += 12800000;
    float* nodeB = (float*)(ws + off); off += 12800000;
    _Float16* Ps = (_Float16*)(ws + off); off += 12800000;
    _Float16* Pn = (_Float16*)(ws + off); off += 12800256;   // +256 B sentinel row
    unsigned short* WcB    = (unsigned short*)(ws + off); off += 3 * 8192 * 2;
    unsigned short* WsnBhi = (unsigned short*)(ws + off); off += 3 * 16384 * 2;
    unsigned short* WsnBlo = (unsigned short*)(ws + off); off += 3 * 16384 * 2;
    float* bias_c = (float*)(ws + off); off += 3 * 128 * 4;

    prep_kernel<<<dim3(72), dim3(256), 0, stream>>>(We, be, W1, b1, W2, b2, W3, b3,
                                                    WcB, WsnBhi, WsnBlo, bias_c, Pn);
    cast_kernel<<<dim3(2 * NBLK), dim3(256), 0, stream>>>(edge_fea, edge_tiles);
    embed_kernel<<<dim3(782), dim3(256), 0, stream>>>(node_fea, Wn, bn, nodeA);

    p_kernel<<<dim3(782), dim3(256), 0, stream>>>(nodeA, WsnBhi, WsnBlo, Ps, Pn);
    conv_kernel<<<dim3(NBLK), dim3(256), 0, stream>>>(nodeA, eidx, edge_tiles, Ps, Pn,
                                                      WcB, bias_c, a1, nodeB);

    p_kernel<<<dim3(782), dim3(256), 0, stream>>>(nodeB, WsnBhi + 16384, WsnBlo + 16384, Ps, Pn);
    conv_kernel<<<dim3(NBLK), dim3(256), 0, stream>>>(nodeB, eidx, edge_tiles, Ps, Pn,
                                                      WcB + 8192, bias_c + 128, a2, nodeA);

    p_kernel<<<dim3(782), dim3(256), 0, stream>>>(nodeA, WsnBhi + 32768, WsnBlo + 32768, Ps, Pn);
    conv_kernel<<<dim3(NBLK), dim3(256), 0, stream>>>(nodeA, eidx, edge_tiles, Ps, Pn,
                                                      WcB + 16384, bias_c + 256, a3, out);
}

// Round 7
// 601.382 us; speedup vs baseline: 1.0654x; 1.0654x over previous
//
#include <hip/hip_runtime.h>
#include <cstdint>
#include <cstddef>

// Problem constants (fixed by the reference)
#define NN   50000
#define MM   24
#define FNIN 92
#define FEIN 41
#define NBLK 3125            // NN / 16 nodes per conv block
#define EROW 48              // edge row padded 41 -> 48 bf16 (96 B)
#define ETILE (MM * 16 * EROW)  // 18432 elems per node-block tile
#define LOG2E 1.4426950408889634f
#define LN2   0.6931471805599453f

typedef __attribute__((ext_vector_type(8))) short bf16x8;
typedef __attribute__((ext_vector_type(4))) float f32x4;
typedef __attribute__((ext_vector_type(8))) unsigned short u16x8;
typedef __attribute__((ext_vector_type(2))) _Float16 f16x2;

__device__ __forceinline__ unsigned short f2bf(float x) {
    unsigned int u = __float_as_uint(x);
    return (unsigned short)((u + 0x7fffu + ((u >> 16) & 1u)) >> 16);  // RNE
}
__device__ __forceinline__ float bf2f(unsigned short h) {
    return __uint_as_float(((unsigned int)h) << 16);
}
__device__ __forceinline__ _Float16 f2h_clamp(float x) {
    return (_Float16)fminf(fmaxf(x, -60000.f), 60000.f);   // stay finite in fp16
}
__device__ __forceinline__ float exp2f_fast(float x) {
#if __has_builtin(__builtin_amdgcn_exp2f)
    return __builtin_amdgcn_exp2f(x);
#else
    float r; asm("v_exp_f32 %0, %1" : "=v"(r) : "v"(x)); return r;
#endif
}
__device__ __forceinline__ float log2f_fast(float x) {
#if __has_builtin(__builtin_amdgcn_logf)
    return __builtin_amdgcn_logf(x);
#else
    float r; asm("v_log_f32 %0, %1" : "=v"(r) : "v"(x)); return r;
#endif
}

// GATE PRE-SCALING: all inputs to the gated sum (WcB, WsnB -> Ps/Pn, bias_c)
// are multiplied by log2e at prep time, so conv computes gf' = gf*log2e and
// can use native exp2/log2 with no range-reduction muls:
//   sigmoid(gf)  = rcp(1 + exp2(-gf'))
//   softplus(gc) = ln2 * (max(gc',0) + log2(1 + exp2(-|gc'|)))   (ln2 deferred)
// Pn sentinel row at node==NN: filter=-60000 (exp2 overflows -> sigmoid=+0),
// core=0 -> padded neighbors contribute exactly 0; no mask ops in the loop.
//
// FUSION (this round): standalone p_kernel removed. P_{l+1} is produced as an
// epilogue of its producer (embed -> P1, conv1 -> P2, conv2 -> P3): each block
// owns the complete output rows of its nodes, so the 16x256 (resp 64x256)
// P-GEMM is block-local via a small LDS stage. Ps/Pn are DOUBLE-BUFFERED
// (A/B) because conv_l's epilogue writes layer-l+1 P while other blocks still
// gather layer-l P.

// ---------------------------------------------------------------------------
// prep: build per-layer combined weights in MFMA B-fragment order + Pn
// sentinels (both buffers).
//   WcB_l : B[k][n] = log2e*(We @ W_l[128:192])[k][n], k<41 else 0.
//   WsnBhi/lo_l: split-bf16 of log2e*W_l[k][n] (n<128 -> Ps) /
//                log2e*W_l[64+k][n-128] (-> Pn).
//   bias_c_l[n] = log2e*(b_l[n] + (be @ W_l[128:192])[n])
// Fragment elem layout: idx = ((j*2+s)*64 + lane)*8 + t ; k = s*32 + (lane>>4)*8 + t ;
//                       n = 16*j + (lane&15)
// ---------------------------------------------------------------------------
__global__ __launch_bounds__(256) void prep_kernel(
    const float* __restrict__ We, const float* __restrict__ be,
    const float* __restrict__ W1, const float* __restrict__ b1,
    const float* __restrict__ W2, const float* __restrict__ b2,
    const float* __restrict__ W3, const float* __restrict__ b3,
    unsigned short* __restrict__ WcB,
    unsigned short* __restrict__ WsnBhi, unsigned short* __restrict__ WsnBlo,
    float* __restrict__ bias_c, _Float16* __restrict__ PnA,
    _Float16* __restrict__ PnB)
{
    __shared__ float Wu_s[64 * 128];     // W rows 128..191 (32 KB)
    __shared__ float We_s[FEIN * 64];    // 10.5 KB
    int l = blockIdx.x / 24;
    int part = blockIdx.x % 24;
    const float* W  = (l == 0) ? W1 : (l == 1) ? W2 : W3;
    const float* bl = (l == 0) ? b1 : (l == 1) ? b2 : b3;
    int tid = threadIdx.x;
    if (blockIdx.x == 0 && tid < 128) {
        // sentinel rows: filter (even) = -60000, core (odd) = 0
        _Float16 sv = (tid & 1) ? (_Float16)0.f : (_Float16)(-60000.f);
        PnA[(size_t)NN * 128 + tid] = sv;
        PnB[(size_t)NN * 128 + tid] = sv;
    }
    if (part < 8) {
        for (int i = tid; i < 64 * 128; i += 256) Wu_s[i] = W[128 * 128 + i];
        for (int i = tid; i < FEIN * 64; i += 256) We_s[i] = We[i];
        __syncthreads();
        int j = part;
        for (int e = tid; e < 1024; e += 256) {
            int s = e >> 9, L = (e >> 3) & 63, t = e & 7;
            int k = s * 32 + ((L >> 4) << 3) + t;
            int n = 16 * j + (L & 15);
            float v = 0.f;
            if (k < FEIN) {
                for (int i = 0; i < 64; ++i)
                    v += We_s[k * 64 + i] * Wu_s[i * 128 + n];
            }
            WcB[l * 8192 + j * 1024 + e] = f2bf(v * LOG2E);
        }
        if (part == 0 && tid < 128) {
            float v = bl[tid];
            for (int i = 0; i < 64; ++i)
                v += be[i] * Wu_s[i * 128 + tid];
            bias_c[l * 128 + tid] = v * LOG2E;
        }
    } else {
        int j = part - 8;
        for (int e = tid; e < 1024; e += 256) {
            int s = e >> 9, L = (e >> 3) & 63, t = e & 7;
            int k = s * 32 + ((L >> 4) << 3) + t;
            int n = 16 * j + (L & 15);
            float v = (n < 128) ? W[k * 128 + n] : W[(64 + k) * 128 + (n - 128)];
            v *= LOG2E;
            unsigned short h = f2bf(v);
            WsnBhi[l * 16384 + j * 1024 + e] = h;
            WsnBlo[l * 16384 + j * 1024 + e] = f2bf(v - bf2f(h));
        }
    }
}

// ---------------------------------------------------------------------------
// cast: edge_fea (N,M,41) fp32 -> block-tiled bf16, m-major rows, k padded
// to 48. 8 nodes per block: coalesced float4 read -> LDS -> transposed ushort8
// (16 B) stores.
// ---------------------------------------------------------------------------
#define CN 8                      // nodes per cast block
__global__ __launch_bounds__(256) void cast_kernel(
    const float* __restrict__ edge_fea, unsigned short* __restrict__ edge_tiles)
{
    __shared__ float s[CN * MM * FEIN];   // 7872 floats = 31.5 KB
    int B = blockIdx.x;
    int b = B >> 1, half = B & 1;
    const float4* src = (const float4*)(edge_fea + ((size_t)b * 16 + half * CN) * (MM * FEIN));
    float4* sd = (float4*)s;
    for (int i = threadIdx.x; i < (CN * MM * FEIN) / 4; i += 256)
        sd[i] = src[i];
    __syncthreads();
    unsigned short* dst = edge_tiles + (size_t)b * ETILE;
    for (int c = threadIdx.x; c < CN * MM * 6; c += 256) {   // 6 chunks of 8 per row
        int r = c / 6, cc = c - r * 6;
        int m = r >> 3, nbl = r & 7;          // 192 rows: m-major over 8 local nodes
        int k0 = cc * 8;
        const float* srow = &s[(nbl * MM + m) * FEIN];
        u16x8 v;
        #pragma unroll
        for (int j = 0; j < 8; ++j) {
            int k = k0 + j;
            v[j] = (k < FEIN) ? f2bf(srow[k]) : (unsigned short)0;
        }
        *(u16x8*)(dst + (size_t)(m * 16 + half * CN + nbl) * EROW + k0) = v;
    }
}

// ---------------------------------------------------------------------------
// embed_p: node0 = node_fea @ Wn + bn (fp32 VALU, exact), THEN fused P1
// epilogue: reuse w_s as x_s[64][68], stage node0, run the split-bf16 P-GEMM
// (wave w owns M-tile rows 16w..16w+15, all 8 jp pairs).
// ---------------------------------------------------------------------------
__global__ __launch_bounds__(256) void embed_p_kernel(
    const float* __restrict__ node_fea, const float* __restrict__ Wn,
    const float* __restrict__ bn, float* __restrict__ node_out,
    const unsigned short* __restrict__ Bhi, const unsigned short* __restrict__ Blo,
    _Float16* __restrict__ Ps, _Float16* __restrict__ Pn)
{
    __shared__ float w_s[FNIN * 64];      // 23.5 KB; reused as x_s (needs 17 KB)
    __shared__ float f_s[64 * FNIN];
    int tid = threadIdx.x;
    int base = blockIdx.x * 64;
    int cnt = min(64, NN - base);
    for (int i = tid; i < FNIN * 64; i += 256) w_s[i] = Wn[i];
    for (int i = tid; i < cnt * FNIN; i += 256) f_s[i] = node_fea[base * FNIN + i];
    __syncthreads();
    int c = tid & 63, g = tid >> 6;
    float acc[16];
    #pragma unroll
    for (int jj = 0; jj < 16; ++jj) acc[jj] = 0.f;
    for (int k = 0; k < FNIN; ++k) {
        float wv = w_s[k * 64 + c];               // conflict-free
        #pragma unroll
        for (int jj = 0; jj < 16; ++jj)
            acc[jj] += f_s[(g + 4 * jj) * FNIN + k] * wv;   // wave-broadcast
    }
    float bv = bn[c];
    __syncthreads();                   // all w_s reads done before reuse
    float* x_s = w_s;                  // [64][68]
    #pragma unroll
    for (int jj = 0; jj < 16; ++jj) {
        int n = g + 4 * jj;
        float v = acc[jj] + bv;
        if (n < cnt) node_out[(base + n) * 64 + c] = v;
        x_s[n * 68 + c] = v;           // rows >= cnt: finite garbage, stores guarded
    }
    __syncthreads();

    // ---- fused P1 ----
    int w = tid >> 6, L = tid & 63, quad = L >> 4, lc = L & 15;
    const float* ap = &x_s[(16 * w + lc) * 68 + quad * 8];
    bf16x8 a0h, a0l, a1h, a1l;
    for (int t = 0; t < 8; ++t) {
        float x0 = ap[t];                   // k = quad*8 + t
        float x1 = ap[32 + t];              // k = 32 + quad*8 + t
        unsigned short h0 = f2bf(x0), h1 = f2bf(x1);
        a0h[t] = (short)h0; a1h[t] = (short)h1;
        a0l[t] = (short)f2bf(x0 - bf2f(h0));
        a1l[t] = (short)f2bf(x1 - bf2f(h1));
    }
    const bf16x8* bh = (const bf16x8*)Bhi;
    const bf16x8* bl = (const bf16x8*)Blo;
    #pragma unroll
    for (int jp = 0; jp < 8; ++jp) {
        int jf = (jp < 4) ? jp : (jp + 4);       // filter tile
        int jc = jf + 4;                         // core tile
        bf16x8 f0h = bh[(jf * 2 + 0) * 64 + L];
        bf16x8 f1h = bh[(jf * 2 + 1) * 64 + L];
        bf16x8 f0l = bl[(jf * 2 + 0) * 64 + L];
        bf16x8 f1l = bl[(jf * 2 + 1) * 64 + L];
        bf16x8 c0h = bh[(jc * 2 + 0) * 64 + L];
        bf16x8 c1h = bh[(jc * 2 + 1) * 64 + L];
        bf16x8 c0l = bl[(jc * 2 + 0) * 64 + L];
        bf16x8 c1l = bl[(jc * 2 + 1) * 64 + L];
        f32x4 Cf = {0.f, 0.f, 0.f, 0.f}, Cc = {0.f, 0.f, 0.f, 0.f};
        Cf = __builtin_amdgcn_mfma_f32_16x16x32_bf16(a0h, f0h, Cf, 0, 0, 0);
        Cf = __builtin_amdgcn_mfma_f32_16x16x32_bf16(a1h, f1h, Cf, 0, 0, 0);
        Cf = __builtin_amdgcn_mfma_f32_16x16x32_bf16(a0l, f0h, Cf, 0, 0, 0);
        Cf = __builtin_amdgcn_mfma_f32_16x16x32_bf16(a1l, f1h, Cf, 0, 0, 0);
        Cf = __builtin_amdgcn_mfma_f32_16x16x32_bf16(a0h, f0l, Cf, 0, 0, 0);
        Cf = __builtin_amdgcn_mfma_f32_16x16x32_bf16(a1h, f1l, Cf, 0, 0, 0);
        Cc = __builtin_amdgcn_mfma_f32_16x16x32_bf16(a0h, c0h, Cc, 0, 0, 0);
        Cc = __builtin_amdgcn_mfma_f32_16x16x32_bf16(a1h, c1h, Cc, 0, 0, 0);
        Cc = __builtin_amdgcn_mfma_f32_16x16x32_bf16(a0l, c0h, Cc, 0, 0, 0);
        Cc = __builtin_amdgcn_mfma_f32_16x16x32_bf16(a1l, c1h, Cc, 0, 0, 0);
        Cc = __builtin_amdgcn_mfma_f32_16x16x32_bf16(a0h, c0l, Cc, 0, 0, 0);
        Cc = __builtin_amdgcn_mfma_f32_16x16x32_bf16(a1h, c1l, Cc, 0, 0, 0);
        int cl = (jp < 4) ? (16 * jp + lc) : (16 * (jp - 4) + lc);
        _Float16* P = (jp < 4) ? Ps : Pn;
        #pragma unroll
        for (int r = 0; r < 4; ++r) {
            int nr = 16 * w + quad * 4 + r;
            if (nr < cnt) {
                f16x2 v = {f2h_clamp(Cf[r]), f2h_clamp(Cc[r])};
                *(f16x2*)&P[(size_t)(base + nr) * 128 + 2 * cl] = v;
            }
        }
    }
}

// ---------------------------------------------------------------------------
// conv: one layer (R4 main loop verbatim: 2x-unrolled rolling loop, offset
// depth-2, value depth-1 -- deeper mod-4 pipeline REGRESSED in R6, full unroll
// REGRESSED in R1). Fused P_{l+1} epilogue when Ps_out != null: stage o into
// x_s[16][68], one 16x256 split-bf16 P-GEMM, wave w covers jp = {2w, 2w+1}.
// ---------------------------------------------------------------------------
__global__ __launch_bounds__(256, 5) void conv_kernel(
    const float* __restrict__ node_in, const int* __restrict__ idx,
    const unsigned short* __restrict__ edge_tiles,
    const _Float16* __restrict__ Ps, const _Float16* __restrict__ Pn,
    const unsigned short* __restrict__ WcB, const float* __restrict__ bias_c,
    const float* __restrict__ alpha_p, float* __restrict__ node_out,
    const unsigned short* __restrict__ NBhi, const unsigned short* __restrict__ NBlo,
    _Float16* __restrict__ Ps_out, _Float16* __restrict__ Pn_out)
{
    __shared__ unsigned ofs_s[16 * 25];     // (gg<<8); stride 25; slot 24 = sentinel
    __shared__ float x_s[16 * 68];          // fused-P stage (4.4 KB)
    int tid = threadIdx.x;
    int b = blockIdx.x;
    int base = b * 16;
    for (int i = tid; i < 16 * MM; i += 256) {
        int row = i / MM, m = i - row * MM;
        int g = idx[base * MM + i];
        unsigned gg = (unsigned)((g >= 0) ? g : NN);   // NN = sentinel row
        ofs_s[row * 25 + m] = gg << 8;                 // byte offset of Pn row
    }
    if (tid < 16) ofs_s[tid * 25 + 24] = ((unsigned)NN) << 8;   // pad -> sentinel
    __syncthreads();

    int w = tid >> 6, L = tid & 63, quad = L >> 4, lc = L & 15;
    int colf = 16 * w + lc;                  // filter col (0..63) == output col
    const bf16x8* wcb = (const bf16x8*)WcB;
    bf16x8 bf0 = wcb[(w * 2 + 0) * 64 + L];        // filter tile j=w, kstep 0
    bf16x8 bf1 = wcb[(w * 2 + 1) * 64 + L];        // kstep 1 (k>=41 rows are zero)
    bf16x8 bc0 = wcb[((w + 4) * 2 + 0) * 64 + L];  // core tile j=w+4
    bf16x8 bc1 = wcb[((w + 4) * 2 + 1) * 64 + L];

    float bias_f = bias_c[colf];
    float bias_g = bias_c[64 + colf];
    float psb_f[4], psb_c[4];
    #pragma unroll
    for (int r = 0; r < 4; ++r) {
        int nr = base + quad * 4 + r;
        f16x2 sp = *(const f16x2*)&Ps[(size_t)nr * 128 + 2 * colf];
        psb_f[r] = (float)sp[0] + bias_f;
        psb_c[r] = (float)sp[1] + bias_g;
    }

    float acc[4] = {0.f, 0.f, 0.f, 0.f};
    const char* PnB_ = (const char*)Pn;
    unsigned coff = (unsigned)colf << 2;         // byte offset of f16x2 pair in a row
    const unsigned* ofsr = &ofs_s[quad * 100];   // rows quad*4..+3, stride 25
    const unsigned short* et = edge_tiles + (size_t)b * ETILE + lc * EROW + quad * 8;

    auto conv_step = [&](const f16x2 (&PN)[4], bf16x8 A0, bf16x8 A1) {
        f32x4 Cf = {psb_f[0], psb_f[1], psb_f[2], psb_f[3]};
        f32x4 Cc = {psb_c[0], psb_c[1], psb_c[2], psb_c[3]};
        Cf = __builtin_amdgcn_mfma_f32_16x16x32_bf16(A0, bf0, Cf, 0, 0, 0);
        Cf = __builtin_amdgcn_mfma_f32_16x16x32_bf16(A1, bf1, Cf, 0, 0, 0);
        Cc = __builtin_amdgcn_mfma_f32_16x16x32_bf16(A0, bc0, Cc, 0, 0, 0);
        Cc = __builtin_amdgcn_mfma_f32_16x16x32_bf16(A1, bc1, Cc, 0, 0, 0);
        #pragma unroll
        for (int r = 0; r < 4; ++r) {
            float gf = Cf[r] + (float)PN[r][0];
            float gc = Cc[r] + (float)PN[r][1];
            float sg = __builtin_amdgcn_rcpf(1.0f + exp2f_fast(-gf));   // sentinel: rcp(inf)=+0
            float sp2 = fmaxf(gc, 0.f)
                      + log2f_fast(1.0f + exp2f_fast(fminf(gc, -gc)));  // -|gc| in 1 op
            acc[r] = fmaf(sg, sp2, acc[r]);
        }
    };

    // ---- prologue: offsets m=0,1,2; values+frags m=0 ----
    unsigned o1[4], o2[4], o3[4];
    f16x2 pnA[4], pnB[4];
    {
        unsigned o0[4];
        #pragma unroll
        for (int r = 0; r < 4; ++r) o0[r] = ofsr[r * 25 + 0];
        #pragma unroll
        for (int r = 0; r < 4; ++r)
            pnA[r] = *(const f16x2*)(PnB_ + (o0[r] + coff));
    }
    bf16x8 aA0 = *(const bf16x8*)(et);
    bf16x8 aA1 = *(const bf16x8*)(et + 32);
    #pragma unroll
    for (int r = 0; r < 4; ++r) o1[r] = ofsr[r * 25 + 1];
    #pragma unroll
    for (int r = 0; r < 4; ++r) o2[r] = ofsr[r * 25 + 2];
    bf16x8 aB0, aB1;

    #pragma unroll 1
    for (int t = 0; t < 12; ++t) {
        int m = 2 * t;
        // ---- half A: prefetch values m+1 (o1), read ofs m+3; compute m ----
        #pragma unroll
        for (int r = 0; r < 4; ++r)
            pnB[r] = *(const f16x2*)(PnB_ + (o1[r] + coff));
        {
            const unsigned short* ep = et + (m + 1) * 768;
            aB0 = *(const bf16x8*)(ep);
            aB1 = *(const bf16x8*)(ep + 32);
        }
        int m3 = min(m + 3, 24);                 // 24 = sentinel pad slot
        #pragma unroll
        for (int r = 0; r < 4; ++r) o3[r] = ofsr[r * 25 + m3];
        conv_step(pnA, aA0, aA1);
        // ---- half B: prefetch values m+2 (o2), read ofs m+4; compute m+1 ----
        #pragma unroll
        for (int r = 0; r < 4; ++r)
            pnA[r] = *(const f16x2*)(PnB_ + (o2[r] + coff));
        {
            int me = min(m + 2, 23);             // t=11: dead reload of m=23 (safe)
            const unsigned short* ep = et + me * 768;
            aA0 = *(const bf16x8*)(ep);
            aA1 = *(const bf16x8*)(ep + 32);
        }
        int m4 = min(m + 4, 24);
        #pragma unroll
        for (int r = 0; r < 4; ++r) o2[r] = ofsr[r * 25 + m4];
        conv_step(pnB, aB0, aB1);
        // ---- rotate (4 movs per 2 m) ----
        #pragma unroll
        for (int r = 0; r < 4; ++r) o1[r] = o3[r];
    }

    float alpha = alpha_p[0];
    #pragma unroll
    for (int r = 0; r < 4; ++r) {
        int nr = base + quad * 4 + r;
        float x = alpha * node_in[nr * 64 + colf] + acc[r] * LN2;   // back to ln domain
        float o = fmaxf(x, 0.f) + __logf(1.0f + __expf(-fabsf(x)));
        node_out[nr * 64 + colf] = o;
        x_s[(quad * 4 + r) * 68 + colf] = o;     // stage for fused P (2-way banks)
    }

    // ---- fused P_{l+1} epilogue (16 nodes x 256 cols, block-local) ----
    if (Ps_out) {
        __syncthreads();
        const float* ap = &x_s[lc * 68 + quad * 8];
        bf16x8 a0h, a0l, a1h, a1l;
        for (int t = 0; t < 8; ++t) {
            float x0 = ap[t];                   // k = quad*8 + t
            float x1 = ap[32 + t];              // k = 32 + quad*8 + t
            unsigned short h0 = f2bf(x0), h1 = f2bf(x1);
            a0h[t] = (short)h0; a1h[t] = (short)h1;
            a0l[t] = (short)f2bf(x0 - bf2f(h0));
            a1l[t] = (short)f2bf(x1 - bf2f(h1));
        }
        const bf16x8* bh = (const bf16x8*)NBhi;
        const bf16x8* bl = (const bf16x8*)NBlo;
        #pragma unroll
        for (int u = 0; u < 2; ++u) {
            int jp = 2 * w + u;                      // wave w covers jp 2w, 2w+1
            int jf = (jp < 4) ? jp : (jp + 4);
            int jc = jf + 4;
            bf16x8 f0h = bh[(jf * 2 + 0) * 64 + L];
            bf16x8 f1h = bh[(jf * 2 + 1) * 64 + L];
            bf16x8 f0l = bl[(jf * 2 + 0) * 64 + L];
            bf16x8 f1l = bl[(jf * 2 + 1) * 64 + L];
            bf16x8 c0h = bh[(jc * 2 + 0) * 64 + L];
            bf16x8 c1h = bh[(jc * 2 + 1) * 64 + L];
            bf16x8 c0l = bl[(jc * 2 + 0) * 64 + L];
            bf16x8 c1l = bl[(jc * 2 + 1) * 64 + L];
            f32x4 Cf = {0.f, 0.f, 0.f, 0.f}, Cc = {0.f, 0.f, 0.f, 0.f};
            Cf = __builtin_amdgcn_mfma_f32_16x16x32_bf16(a0h, f0h, Cf, 0, 0, 0);
            Cf = __builtin_amdgcn_mfma_f32_16x16x32_bf16(a1h, f1h, Cf, 0, 0, 0);
            Cf = __builtin_amdgcn_mfma_f32_16x16x32_bf16(a0l, f0h, Cf, 0, 0, 0);
            Cf = __builtin_amdgcn_mfma_f32_16x16x32_bf16(a1l, f1h, Cf, 0, 0, 0);
            Cf = __builtin_amdgcn_mfma_f32_16x16x32_bf16(a0h, f0l, Cf, 0, 0, 0);
            Cf = __builtin_amdgcn_mfma_f32_16x16x32_bf16(a1h, f1l, Cf, 0, 0, 0);
            Cc = __builtin_amdgcn_mfma_f32_16x16x32_bf16(a0h, c0h, Cc, 0, 0, 0);
            Cc = __builtin_amdgcn_mfma_f32_16x16x32_bf16(a1h, c1h, Cc, 0, 0, 0);
            Cc = __builtin_amdgcn_mfma_f32_16x16x32_bf16(a0l, c0h, Cc, 0, 0, 0);
            Cc = __builtin_amdgcn_mfma_f32_16x16x32_bf16(a1l, c1h, Cc, 0, 0, 0);
            Cc = __builtin_amdgcn_mfma_f32_16x16x32_bf16(a0h, c0l, Cc, 0, 0, 0);
            Cc = __builtin_amdgcn_mfma_f32_16x16x32_bf16(a1h, c1l, Cc, 0, 0, 0);
            int cl = (jp < 4) ? (16 * jp + lc) : (16 * (jp - 4) + lc);
            _Float16* P = (jp < 4) ? Ps_out : Pn_out;
            #pragma unroll
            for (int r = 0; r < 4; ++r) {
                int nr = quad * 4 + r;               // all 16 nodes valid
                f16x2 v = {f2h_clamp(Cf[r]), f2h_clamp(Cc[r])};
                *(f16x2*)&P[(size_t)(base + nr) * 128 + 2 * cl] = v;
            }
        }
    }
}

// ---------------------------------------------------------------------------
extern "C" void kernel_launch(void* const* d_in, const int* in_sizes, int n_in,
                              void* d_out, int out_size, void* d_ws, size_t ws_size,
                              hipStream_t stream)
{
    const float* node_fea = (const float*)d_in[0];
    const float* edge_fea = (const float*)d_in[1];
    const int*   eidx     = (const int*)d_in[2];
    const float* Wn = (const float*)d_in[3];
    const float* bn = (const float*)d_in[4];
    const float* We = (const float*)d_in[5];
    const float* be = (const float*)d_in[6];
    const float* W1 = (const float*)d_in[7];
    const float* b1 = (const float*)d_in[8];
    const float* a1 = (const float*)d_in[9];
    const float* W2 = (const float*)d_in[10];
    const float* b2 = (const float*)d_in[11];
    const float* a2 = (const float*)d_in[12];
    const float* W3 = (const float*)d_in[13];
    const float* b3 = (const float*)d_in[14];
    const float* a3 = (const float*)d_in[15];
    float* out = (float*)d_out;

    // Workspace layout (~193 MiB total)
    char* ws = (char*)d_ws;
    unsigned short* edge_tiles = (unsigned short*)ws;   // 115,200,000 B + 4 KB pad
    size_t off = 115204352;                             // (conv prefetch over-read pad)
    float* nodeA = (float*)(ws + off); off += 12800000;
    float* nodeB = (float*)(ws + off); off += 12800000;
    _Float16* PsA = (_Float16*)(ws + off); off += 12800000;
    _Float16* PnA = (_Float16*)(ws + off); off += 12800256;   // +256 B sentinel row
    _Float16* PsB = (_Float16*)(ws + off); off += 12800000;
    _Float16* PnB = (_Float16*)(ws + off); off += 12800256;   // +256 B sentinel row
    unsigned short* WcB    = (unsigned short*)(ws + off); off += 3 * 8192 * 2;
    unsigned short* WsnBhi = (unsigned short*)(ws + off); off += 3 * 16384 * 2;
    unsigned short* WsnBlo = (unsigned short*)(ws + off); off += 3 * 16384 * 2;
    float* bias_c = (float*)(ws + off); off += 3 * 128 * 4;

    prep_kernel<<<dim3(72), dim3(256), 0, stream>>>(We, be, W1, b1, W2, b2, W3, b3,
                                                    WcB, WsnBhi, WsnBlo, bias_c,
                                                    PnA, PnB);
    cast_kernel<<<dim3(2 * NBLK), dim3(256), 0, stream>>>(edge_fea, edge_tiles);

    // embed + fused P1 -> A buffers
    embed_p_kernel<<<dim3(782), dim3(256), 0, stream>>>(node_fea, Wn, bn, nodeA,
                                                        WsnBhi, WsnBlo, PsA, PnA);
    // conv1 (reads A) + fused P2 -> B buffers
    conv_kernel<<<dim3(NBLK), dim3(256), 0, stream>>>(nodeA, eidx, edge_tiles, PsA, PnA,
                                                      WcB, bias_c, a1, nodeB,
                                                      WsnBhi + 16384, WsnBlo + 16384,
                                                      PsB, PnB);
    // conv2 (reads B) + fused P3 -> A buffers
    conv_kernel<<<dim3(NBLK), dim3(256), 0, stream>>>(nodeB, eidx, edge_tiles, PsB, PnB,
                                                      WcB + 8192, bias_c + 128, a2, nodeA,
                                                      WsnBhi + 32768, WsnBlo + 32768,
                                                      PsA, PnA);
    // conv3 (reads A), no fused P
    conv_kernel<<<dim3(NBLK), dim3(256), 0, stream>>>(nodeA, eidx, edge_tiles, PsA, PnA,
                                                      WcB + 16384, bias_c + 256, a3, out,
                                                      nullptr, nullptr, nullptr, nullptr);
}

// Round 8
// 577.806 us; speedup vs baseline: 1.1088x; 1.0408x over previous
//
#include <hip/hip_runtime.h>
#include <cstdint>
#include <cstddef>

// Problem constants (fixed by the reference)
#define NN   50000
#define MM   24
#define FNIN 92
#define FEIN 41
#define NBLK 3125            // NN / 16 nodes per conv block
#define EROW 48              // edge row padded 41 -> 48 bf16 (96 B)
#define ETILE (MM * 16 * EROW)  // 18432 elems per node-block tile
#define LOG2E 1.4426950408889634f
#define LN2   0.6931471805599453f

typedef __attribute__((ext_vector_type(8))) short bf16x8;
typedef __attribute__((ext_vector_type(4))) float f32x4;
typedef __attribute__((ext_vector_type(8))) unsigned short u16x8;
typedef __attribute__((ext_vector_type(2))) _Float16 f16x2;

__device__ __forceinline__ unsigned short f2bf(float x) {
    unsigned int u = __float_as_uint(x);
    return (unsigned short)((u + 0x7fffu + ((u >> 16) & 1u)) >> 16);  // RNE
}
__device__ __forceinline__ float bf2f(unsigned short h) {
    return __uint_as_float(((unsigned int)h) << 16);
}
__device__ __forceinline__ _Float16 f2h_clamp(float x) {
    return (_Float16)fminf(fmaxf(x, -60000.f), 60000.f);   // stay finite in fp16
}
__device__ __forceinline__ float exp2f_fast(float x) {
#if __has_builtin(__builtin_amdgcn_exp2f)
    return __builtin_amdgcn_exp2f(x);
#else
    float r; asm("v_exp_f32 %0, %1" : "=v"(r) : "v"(x)); return r;
#endif
}
__device__ __forceinline__ float log2f_fast(float x) {
#if __has_builtin(__builtin_amdgcn_logf)
    return __builtin_amdgcn_logf(x);
#else
    float r; asm("v_log_f32 %0, %1" : "=v"(r) : "v"(x)); return r;
#endif
}

// GATE PRE-SCALING: all inputs to the gated sum (WcB, WsnB -> Ps/Pn, bias_c)
// are multiplied by log2e at prep time, so conv computes gf' = gf*log2e and
// can use native exp2/log2 with no range-reduction muls:
//   sigmoid(gf)  = rcp(1 + exp2(-gf'))
//   softplus(gc) = ln2 * (max(gc',0) + log2(1 + exp2(-|gc'|)))   (ln2 deferred)
// Pn sentinel row at node==NN: filter=-60000 (exp2 overflows -> sigmoid=+0),
// core=0 -> padded neighbors contribute exactly 0; no mask ops in the loop.
//
// FUSION: P_{l+1} produced as epilogue of its producer (pre -> P1, conv1 -> P2,
// conv2 -> P3); Ps/Pn double-buffered A/B. THIS ROUND: cast and embed merged
// into ONE kernel (interleaved grid 1:8) so memory-bound cast blocks overlap
// compute-bound embed blocks on each CU; conv folds gathered pn into the MFMA
// C operand (C = psb + pn) removing the 8 C-init movs + 8 post-MFMA adds.

// ---------------------------------------------------------------------------
// prep: build per-layer combined weights in MFMA B-fragment order + Pn
// sentinels (both buffers).
// Fragment elem layout: idx = ((j*2+s)*64 + lane)*8 + t ; k = s*32 + (lane>>4)*8 + t ;
//                       n = 16*j + (lane&15)
// ---------------------------------------------------------------------------
__global__ __launch_bounds__(256) void prep_kernel(
    const float* __restrict__ We, const float* __restrict__ be,
    const float* __restrict__ W1, const float* __restrict__ b1,
    const float* __restrict__ W2, const float* __restrict__ b2,
    const float* __restrict__ W3, const float* __restrict__ b3,
    unsigned short* __restrict__ WcB,
    unsigned short* __restrict__ WsnBhi, unsigned short* __restrict__ WsnBlo,
    float* __restrict__ bias_c, _Float16* __restrict__ PnA,
    _Float16* __restrict__ PnB)
{
    __shared__ float Wu_s[64 * 128];     // W rows 128..191 (32 KB)
    __shared__ float We_s[FEIN * 64];    // 10.5 KB
    int l = blockIdx.x / 24;
    int part = blockIdx.x % 24;
    const float* W  = (l == 0) ? W1 : (l == 1) ? W2 : W3;
    const float* bl = (l == 0) ? b1 : (l == 1) ? b2 : b3;
    int tid = threadIdx.x;
    if (blockIdx.x == 0 && tid < 128) {
        // sentinel rows: filter (even) = -60000, core (odd) = 0
        _Float16 sv = (tid & 1) ? (_Float16)0.f : (_Float16)(-60000.f);
        PnA[(size_t)NN * 128 + tid] = sv;
        PnB[(size_t)NN * 128 + tid] = sv;
    }
    if (part < 8) {
        for (int i = tid; i < 64 * 128; i += 256) Wu_s[i] = W[128 * 128 + i];
        for (int i = tid; i < FEIN * 64; i += 256) We_s[i] = We[i];
        __syncthreads();
        int j = part;
        for (int e = tid; e < 1024; e += 256) {
            int s = e >> 9, L = (e >> 3) & 63, t = e & 7;
            int k = s * 32 + ((L >> 4) << 3) + t;
            int n = 16 * j + (L & 15);
            float v = 0.f;
            if (k < FEIN) {
                for (int i = 0; i < 64; ++i)
                    v += We_s[k * 64 + i] * Wu_s[i * 128 + n];
            }
            WcB[l * 8192 + j * 1024 + e] = f2bf(v * LOG2E);
        }
        if (part == 0 && tid < 128) {
            float v = bl[tid];
            for (int i = 0; i < 64; ++i)
                v += be[i] * Wu_s[i * 128 + tid];
            bias_c[l * 128 + tid] = v * LOG2E;
        }
    } else {
        int j = part - 8;
        for (int e = tid; e < 1024; e += 256) {
            int s = e >> 9, L = (e >> 3) & 63, t = e & 7;
            int k = s * 32 + ((L >> 4) << 3) + t;
            int n = 16 * j + (L & 15);
            float v = (n < 128) ? W[k * 128 + n] : W[(64 + k) * 128 + (n - 128)];
            v *= LOG2E;
            unsigned short h = f2bf(v);
            WsnBhi[l * 16384 + j * 1024 + e] = h;
            WsnBlo[l * 16384 + j * 1024 + e] = f2bf(v - bf2f(h));
        }
    }
}

// ---------------------------------------------------------------------------
// pre: merged cast + embed(+fused P1). Interleaved grid (7032 blocks):
// b%9==0 -> embed block b/9 (782 total); else cast block (6250 total).
// Memory-bound cast blocks and compute-bound embed blocks co-resident per CU.
//   cast: edge_fea (N,M,41) fp32 -> block-tiled bf16, m-major rows, k pad 48.
//   embed: node0 = node_fea @ Wn + bn (fp32 VALU, exact), then fused P1
//          epilogue (split-bf16 MFMA P-GEMM) into PsA/PnA.
// ---------------------------------------------------------------------------
#define CN 8                      // nodes per cast block
__global__ __launch_bounds__(256) void pre_kernel(
    const float* __restrict__ edge_fea, unsigned short* __restrict__ edge_tiles,
    const float* __restrict__ node_fea, const float* __restrict__ Wn,
    const float* __restrict__ bn, float* __restrict__ node_out,
    const unsigned short* __restrict__ Bhi, const unsigned short* __restrict__ Blo,
    _Float16* __restrict__ Ps, _Float16* __restrict__ Pn)
{
    __shared__ char smem[47104];          // max(embed 46 KB, cast 31.5 KB)
    int bb = blockIdx.x;
    int tid = threadIdx.x;

    if ((bb % 9) == 0) {
        // ================= embed + fused P1 =================
        int base = (bb / 9) * 64;
        float* w_s = (float*)smem;                 // [FNIN*64] then reused as x_s
        float* f_s = (float*)(smem + FNIN * 64 * 4);
        int cnt = min(64, NN - base);
        for (int i = tid; i < FNIN * 64; i += 256) w_s[i] = Wn[i];
        for (int i = tid; i < cnt * FNIN; i += 256) f_s[i] = node_fea[base * FNIN + i];
        __syncthreads();
        int c = tid & 63, g = tid >> 6;
        float acc[16];
        #pragma unroll
        for (int jj = 0; jj < 16; ++jj) acc[jj] = 0.f;
        for (int k = 0; k < FNIN; ++k) {
            float wv = w_s[k * 64 + c];               // conflict-free
            #pragma unroll
            for (int jj = 0; jj < 16; ++jj)
                acc[jj] += f_s[(g + 4 * jj) * FNIN + k] * wv;   // wave-broadcast
        }
        float bv = bn[c];
        __syncthreads();                   // all w_s reads done before reuse
        float* x_s = w_s;                  // [64][68]
        #pragma unroll
        for (int jj = 0; jj < 16; ++jj) {
            int n = g + 4 * jj;
            float v = acc[jj] + bv;
            if (n < cnt) node_out[(base + n) * 64 + c] = v;
            x_s[n * 68 + c] = v;           // rows >= cnt: finite garbage, stores guarded
        }
        __syncthreads();

        // ---- fused P1 ----
        int w = tid >> 6, L = tid & 63, quad = L >> 4, lc = L & 15;
        const float* ap = &x_s[(16 * w + lc) * 68 + quad * 8];
        bf16x8 a0h, a0l, a1h, a1l;
        for (int t = 0; t < 8; ++t) {
            float x0 = ap[t];                   // k = quad*8 + t
            float x1 = ap[32 + t];              // k = 32 + quad*8 + t
            unsigned short h0 = f2bf(x0), h1 = f2bf(x1);
            a0h[t] = (short)h0; a1h[t] = (short)h1;
            a0l[t] = (short)f2bf(x0 - bf2f(h0));
            a1l[t] = (short)f2bf(x1 - bf2f(h1));
        }
        const bf16x8* bh = (const bf16x8*)Bhi;
        const bf16x8* bl = (const bf16x8*)Blo;
        #pragma unroll
        for (int jp = 0; jp < 8; ++jp) {
            int jf = (jp < 4) ? jp : (jp + 4);       // filter tile
            int jc = jf + 4;                         // core tile
            bf16x8 f0h = bh[(jf * 2 + 0) * 64 + L];
            bf16x8 f1h = bh[(jf * 2 + 1) * 64 + L];
            bf16x8 f0l = bl[(jf * 2 + 0) * 64 + L];
            bf16x8 f1l = bl[(jf * 2 + 1) * 64 + L];
            bf16x8 c0h = bh[(jc * 2 + 0) * 64 + L];
            bf16x8 c1h = bh[(jc * 2 + 1) * 64 + L];
            bf16x8 c0l = bl[(jc * 2 + 0) * 64 + L];
            bf16x8 c1l = bl[(jc * 2 + 1) * 64 + L];
            f32x4 Cf = {0.f, 0.f, 0.f, 0.f}, Cc = {0.f, 0.f, 0.f, 0.f};
            Cf = __builtin_amdgcn_mfma_f32_16x16x32_bf16(a0h, f0h, Cf, 0, 0, 0);
            Cf = __builtin_amdgcn_mfma_f32_16x16x32_bf16(a1h, f1h, Cf, 0, 0, 0);
            Cf = __builtin_amdgcn_mfma_f32_16x16x32_bf16(a0l, f0h, Cf, 0, 0, 0);
            Cf = __builtin_amdgcn_mfma_f32_16x16x32_bf16(a1l, f1h, Cf, 0, 0, 0);
            Cf = __builtin_amdgcn_mfma_f32_16x16x32_bf16(a0h, f0l, Cf, 0, 0, 0);
            Cf = __builtin_amdgcn_mfma_f32_16x16x32_bf16(a1h, f1l, Cf, 0, 0, 0);
            Cc = __builtin_amdgcn_mfma_f32_16x16x32_bf16(a0h, c0h, Cc, 0, 0, 0);
            Cc = __builtin_amdgcn_mfma_f32_16x16x32_bf16(a1h, c1h, Cc, 0, 0, 0);
            Cc = __builtin_amdgcn_mfma_f32_16x16x32_bf16(a0l, c0h, Cc, 0, 0, 0);
            Cc = __builtin_amdgcn_mfma_f32_16x16x32_bf16(a1l, c1h, Cc, 0, 0, 0);
            Cc = __builtin_amdgcn_mfma_f32_16x16x32_bf16(a0h, c0l, Cc, 0, 0, 0);
            Cc = __builtin_amdgcn_mfma_f32_16x16x32_bf16(a1h, c1l, Cc, 0, 0, 0);
            int cl = (jp < 4) ? (16 * jp + lc) : (16 * (jp - 4) + lc);
            _Float16* P = (jp < 4) ? Ps : Pn;
            #pragma unroll
            for (int r = 0; r < 4; ++r) {
                int nr = 16 * w + quad * 4 + r;
                if (nr < cnt) {
                    f16x2 v = {f2h_clamp(Cf[r]), f2h_clamp(Cc[r])};
                    *(f16x2*)&P[(size_t)(base + nr) * 128 + 2 * cl] = v;
                }
            }
        }
    } else {
        // ================= cast =================
        int nem = (bb + 8) / 9; if (nem > 782) nem = 782;
        int B = bb - nem;                     // cast block id in [0, 6250)
        float* s = (float*)smem;              // CN*MM*FEIN floats = 31.5 KB
        int b = B >> 1, half = B & 1;
        const float4* src = (const float4*)(edge_fea + ((size_t)b * 16 + half * CN) * (MM * FEIN));
        float4* sd = (float4*)s;
        for (int i = tid; i < (CN * MM * FEIN) / 4; i += 256)
            sd[i] = src[i];
        __syncthreads();
        unsigned short* dst = edge_tiles + (size_t)b * ETILE;
        for (int c = tid; c < CN * MM * 6; c += 256) {   // 6 chunks of 8 per row
            int r = c / 6, cc = c - r * 6;
            int m = r >> 3, nbl = r & 7;          // 192 rows: m-major over 8 local nodes
            int k0 = cc * 8;
            const float* srow = &s[(nbl * MM + m) * FEIN];
            u16x8 v;
            #pragma unroll
            for (int j = 0; j < 8; ++j) {
                int k = k0 + j;
                v[j] = (k < FEIN) ? f2bf(srow[k]) : (unsigned short)0;
            }
            *(u16x8*)(dst + (size_t)(m * 16 + half * CN + nbl) * EROW + k0) = v;
        }
    }
}

// ---------------------------------------------------------------------------
// conv: one layer (R4 main loop: 2x-unrolled rolling loop, offset depth-2,
// value depth-1 -- deeper mod-4 pipeline REGRESSED in R6, full unroll
// REGRESSED in R1). THIS ROUND: gathered pn folded into MFMA C-init
// (C = psb + pn) -- removes 8 v_mov + 8 post-MFMA v_add per m; exp2 chain
// starts directly from MFMA output. Fused P_{l+1} epilogue when Ps_out!=null.
// ---------------------------------------------------------------------------
__global__ __launch_bounds__(256, 5) void conv_kernel(
    const float* __restrict__ node_in, const int* __restrict__ idx,
    const unsigned short* __restrict__ edge_tiles,
    const _Float16* __restrict__ Ps, const _Float16* __restrict__ Pn,
    const unsigned short* __restrict__ WcB, const float* __restrict__ bias_c,
    const float* __restrict__ alpha_p, float* __restrict__ node_out,
    const unsigned short* __restrict__ NBhi, const unsigned short* __restrict__ NBlo,
    _Float16* __restrict__ Ps_out, _Float16* __restrict__ Pn_out)
{
    __shared__ unsigned ofs_s[16 * 25];     // (gg<<8); stride 25; slot 24 = sentinel
    __shared__ float x_s[16 * 68];          // fused-P stage (4.4 KB)
    int tid = threadIdx.x;
    int b = blockIdx.x;
    int base = b * 16;
    for (int i = tid; i < 16 * MM; i += 256) {
        int row = i / MM, m = i - row * MM;
        int g = idx[base * MM + i];
        unsigned gg = (unsigned)((g >= 0) ? g : NN);   // NN = sentinel row
        ofs_s[row * 25 + m] = gg << 8;                 // byte offset of Pn row
    }
    if (tid < 16) ofs_s[tid * 25 + 24] = ((unsigned)NN) << 8;   // pad -> sentinel
    __syncthreads();

    int w = tid >> 6, L = tid & 63, quad = L >> 4, lc = L & 15;
    int colf = 16 * w + lc;                  // filter col (0..63) == output col
    const bf16x8* wcb = (const bf16x8*)WcB;
    bf16x8 bf0 = wcb[(w * 2 + 0) * 64 + L];        // filter tile j=w, kstep 0
    bf16x8 bf1 = wcb[(w * 2 + 1) * 64 + L];        // kstep 1 (k>=41 rows are zero)
    bf16x8 bc0 = wcb[((w + 4) * 2 + 0) * 64 + L];  // core tile j=w+4
    bf16x8 bc1 = wcb[((w + 4) * 2 + 1) * 64 + L];

    float bias_f = bias_c[colf];
    float bias_g = bias_c[64 + colf];
    float psb_f[4], psb_c[4];
    #pragma unroll
    for (int r = 0; r < 4; ++r) {
        int nr = base + quad * 4 + r;
        f16x2 sp = *(const f16x2*)&Ps[(size_t)nr * 128 + 2 * colf];
        psb_f[r] = (float)sp[0] + bias_f;
        psb_c[r] = (float)sp[1] + bias_g;
    }

    float acc[4] = {0.f, 0.f, 0.f, 0.f};
    const char* PnB_ = (const char*)Pn;
    unsigned coff = (unsigned)colf << 2;         // byte offset of f16x2 pair in a row
    const unsigned* ofsr = &ofs_s[quad * 100];   // rows quad*4..+3, stride 25
    const unsigned short* et = edge_tiles + (size_t)b * ETILE + lc * EROW + quad * 8;

    auto conv_step = [&](const f16x2 (&PN)[4], bf16x8 A0, bf16x8 A1) {
        f32x4 Cf, Cc;
        #pragma unroll
        for (int r = 0; r < 4; ++r) {        // C init = psb + gathered pn
            Cf[r] = psb_f[r] + (float)PN[r][0];
            Cc[r] = psb_c[r] + (float)PN[r][1];
        }
        Cf = __builtin_amdgcn_mfma_f32_16x16x32_bf16(A0, bf0, Cf, 0, 0, 0);
        Cf = __builtin_amdgcn_mfma_f32_16x16x32_bf16(A1, bf1, Cf, 0, 0, 0);
        Cc = __builtin_amdgcn_mfma_f32_16x16x32_bf16(A0, bc0, Cc, 0, 0, 0);
        Cc = __builtin_amdgcn_mfma_f32_16x16x32_bf16(A1, bc1, Cc, 0, 0, 0);
        #pragma unroll
        for (int r = 0; r < 4; ++r) {
            float gf = Cf[r];
            float gc = Cc[r];
            float sg = __builtin_amdgcn_rcpf(1.0f + exp2f_fast(-gf));   // sentinel: rcp(inf)=+0
            float sp2 = fmaxf(gc, 0.f)
                      + log2f_fast(1.0f + exp2f_fast(fminf(gc, -gc)));  // -|gc| in 1 op
            acc[r] = fmaf(sg, sp2, acc[r]);
        }
    };

    // ---- prologue: offsets m=0,1,2; values+frags m=0 ----
    unsigned o1[4], o2[4], o3[4];
    f16x2 pnA[4], pnB[4];
    {
        unsigned o0[4];
        #pragma unroll
        for (int r = 0; r < 4; ++r) o0[r] = ofsr[r * 25 + 0];
        #pragma unroll
        for (int r = 0; r < 4; ++r)
            pnA[r] = *(const f16x2*)(PnB_ + (o0[r] + coff));
    }
    bf16x8 aA0 = *(const bf16x8*)(et);
    bf16x8 aA1 = *(const bf16x8*)(et + 32);
    #pragma unroll
    for (int r = 0; r < 4; ++r) o1[r] = ofsr[r * 25 + 1];
    #pragma unroll
    for (int r = 0; r < 4; ++r) o2[r] = ofsr[r * 25 + 2];
    bf16x8 aB0, aB1;

    #pragma unroll 1
    for (int t = 0; t < 12; ++t) {
        int m = 2 * t;
        // ---- half A: prefetch values m+1 (o1), read ofs m+3; compute m ----
        #pragma unroll
        for (int r = 0; r < 4; ++r)
            pnB[r] = *(const f16x2*)(PnB_ + (o1[r] + coff));
        {
            const unsigned short* ep = et + (m + 1) * 768;
            aB0 = *(const bf16x8*)(ep);
            aB1 = *(const bf16x8*)(ep + 32);
        }
        int m3 = min(m + 3, 24);                 // 24 = sentinel pad slot
        #pragma unroll
        for (int r = 0; r < 4; ++r) o3[r] = ofsr[r * 25 + m3];
        conv_step(pnA, aA0, aA1);
        // ---- half B: prefetch values m+2 (o2), read ofs m+4; compute m+1 ----
        #pragma unroll
        for (int r = 0; r < 4; ++r)
            pnA[r] = *(const f16x2*)(PnB_ + (o2[r] + coff));
        {
            int me = min(m + 2, 23);             // t=11: dead reload of m=23 (safe)
            const unsigned short* ep = et + me * 768;
            aA0 = *(const bf16x8*)(ep);
            aA1 = *(const bf16x8*)(ep + 32);
        }
        int m4 = min(m + 4, 24);
        #pragma unroll
        for (int r = 0; r < 4; ++r) o2[r] = ofsr[r * 25 + m4];
        conv_step(pnB, aB0, aB1);
        // ---- rotate (4 movs per 2 m) ----
        #pragma unroll
        for (int r = 0; r < 4; ++r) o1[r] = o3[r];
    }

    float alpha = alpha_p[0];
    #pragma unroll
    for (int r = 0; r < 4; ++r) {
        int nr = base + quad * 4 + r;
        float x = alpha * node_in[nr * 64 + colf] + acc[r] * LN2;   // back to ln domain
        float o = fmaxf(x, 0.f) + __logf(1.0f + __expf(-fabsf(x)));
        node_out[nr * 64 + colf] = o;
        x_s[(quad * 4 + r) * 68 + colf] = o;     // stage for fused P (2-way banks)
    }

    // ---- fused P_{l+1} epilogue (16 nodes x 256 cols, block-local) ----
    if (Ps_out) {
        __syncthreads();
        const float* ap = &x_s[lc * 68 + quad * 8];
        bf16x8 a0h, a0l, a1h, a1l;
        for (int t = 0; t < 8; ++t) {
            float x0 = ap[t];                   // k = quad*8 + t
            float x1 = ap[32 + t];              // k = 32 + quad*8 + t
            unsigned short h0 = f2bf(x0), h1 = f2bf(x1);
            a0h[t] = (short)h0; a1h[t] = (short)h1;
            a0l[t] = (short)f2bf(x0 - bf2f(h0));
            a1l[t] = (short)f2bf(x1 - bf2f(h1));
        }
        const bf16x8* bh = (const bf16x8*)NBhi;
        const bf16x8* bl = (const bf16x8*)NBlo;
        #pragma unroll
        for (int u = 0; u < 2; ++u) {
            int jp = 2 * w + u;                      // wave w covers jp 2w, 2w+1
            int jf = (jp < 4) ? jp : (jp + 4);
            int jc = jf + 4;
            bf16x8 f0h = bh[(jf * 2 + 0) * 64 + L];
            bf16x8 f1h = bh[(jf * 2 + 1) * 64 + L];
            bf16x8 f0l = bl[(jf * 2 + 0) * 64 + L];
            bf16x8 f1l = bl[(jf * 2 + 1) * 64 + L];
            bf16x8 c0h = bh[(jc * 2 + 0) * 64 + L];
            bf16x8 c1h = bh[(jc * 2 + 1) * 64 + L];
            bf16x8 c0l = bl[(jc * 2 + 0) * 64 + L];
            bf16x8 c1l = bl[(jc * 2 + 1) * 64 + L];
            f32x4 Cf = {0.f, 0.f, 0.f, 0.f}, Cc = {0.f, 0.f, 0.f, 0.f};
            Cf = __builtin_amdgcn_mfma_f32_16x16x32_bf16(a0h, f0h, Cf, 0, 0, 0);
            Cf = __builtin_amdgcn_mfma_f32_16x16x32_bf16(a1h, f1h, Cf, 0, 0, 0);
            Cf = __builtin_amdgcn_mfma_f32_16x16x32_bf16(a0l, f0h, Cf, 0, 0, 0);
            Cf = __builtin_amdgcn_mfma_f32_16x16x32_bf16(a1l, f1h, Cf, 0, 0, 0);
            Cf = __builtin_amdgcn_mfma_f32_16x16x32_bf16(a0h, f0l, Cf, 0, 0, 0);
            Cf = __builtin_amdgcn_mfma_f32_16x16x32_bf16(a1h, f1l, Cf, 0, 0, 0);
            Cc = __builtin_amdgcn_mfma_f32_16x16x32_bf16(a0h, c0h, Cc, 0, 0, 0);
            Cc = __builtin_amdgcn_mfma_f32_16x16x32_bf16(a1h, c1h, Cc, 0, 0, 0);
            Cc = __builtin_amdgcn_mfma_f32_16x16x32_bf16(a0l, c0h, Cc, 0, 0, 0);
            Cc = __builtin_amdgcn_mfma_f32_16x16x32_bf16(a1l, c1h, Cc, 0, 0, 0);
            Cc = __builtin_amdgcn_mfma_f32_16x16x32_bf16(a0h, c0l, Cc, 0, 0, 0);
            Cc = __builtin_amdgcn_mfma_f32_16x16x32_bf16(a1h, c1l, Cc, 0, 0, 0);
            int cl = (jp < 4) ? (16 * jp + lc) : (16 * (jp - 4) + lc);
            _Float16* P = (jp < 4) ? Ps_out : Pn_out;
            #pragma unroll
            for (int r = 0; r < 4; ++r) {
                int nr = quad * 4 + r;               // all 16 nodes valid
                f16x2 v = {f2h_clamp(Cf[r]), f2h_clamp(Cc[r])};
                *(f16x2*)&P[(size_t)(base + nr) * 128 + 2 * cl] = v;
            }
        }
    }
}

// ---------------------------------------------------------------------------
extern "C" void kernel_launch(void* const* d_in, const int* in_sizes, int n_in,
                              void* d_out, int out_size, void* d_ws, size_t ws_size,
                              hipStream_t stream)
{
    const float* node_fea = (const float*)d_in[0];
    const float* edge_fea = (const float*)d_in[1];
    const int*   eidx     = (const int*)d_in[2];
    const float* Wn = (const float*)d_in[3];
    const float* bn = (const float*)d_in[4];
    const float* We = (const float*)d_in[5];
    const float* be = (const float*)d_in[6];
    const float* W1 = (const float*)d_in[7];
    const float* b1 = (const float*)d_in[8];
    const float* a1 = (const float*)d_in[9];
    const float* W2 = (const float*)d_in[10];
    const float* b2 = (const float*)d_in[11];
    const float* a2 = (const float*)d_in[12];
    const float* W3 = (const float*)d_in[13];
    const float* b3 = (const float*)d_in[14];
    const float* a3 = (const float*)d_in[15];
    float* out = (float*)d_out;

    // Workspace layout (~193 MiB total)
    char* ws = (char*)d_ws;
    unsigned short* edge_tiles = (unsigned short*)ws;   // 115,200,000 B + 4 KB pad
    size_t off = 115204352;                             // (conv prefetch over-read pad)
    float* nodeA = (float*)(ws + off); off += 12800000;
    float* nodeB = (float*)(ws + off); off += 12800000;
    _Float16* PsA = (_Float16*)(ws + off); off += 12800000;
    _Float16* PnA = (_Float16*)(ws + off); off += 12800256;   // +256 B sentinel row
    _Float16* PsB = (_Float16*)(ws + off); off += 12800000;
    _Float16* PnB = (_Float16*)(ws + off); off += 12800256;   // +256 B sentinel row
    unsigned short* WcB    = (unsigned short*)(ws + off); off += 3 * 8192 * 2;
    unsigned short* WsnBhi = (unsigned short*)(ws + off); off += 3 * 16384 * 2;
    unsigned short* WsnBlo = (unsigned short*)(ws + off); off += 3 * 16384 * 2;
    float* bias_c = (float*)(ws + off); off += 3 * 128 * 4;

    prep_kernel<<<dim3(72), dim3(256), 0, stream>>>(We, be, W1, b1, W2, b2, W3, b3,
                                                    WcB, WsnBhi, WsnBlo, bias_c,
                                                    PnA, PnB);
    // merged cast + embed(+P1): 6250 cast blocks + 782 embed blocks, 1:8 interleave
    pre_kernel<<<dim3(7032), dim3(256), 0, stream>>>(edge_fea, edge_tiles,
                                                     node_fea, Wn, bn, nodeA,
                                                     WsnBhi, WsnBlo, PsA, PnA);
    // conv1 (reads A) + fused P2 -> B buffers
    conv_kernel<<<dim3(NBLK), dim3(256), 0, stream>>>(nodeA, eidx, edge_tiles, PsA, PnA,
                                                      WcB, bias_c, a1, nodeB,
                                                      WsnBhi + 16384, WsnBlo + 16384,
                                                      PsB, PnB);
    // conv2 (reads B) + fused P3 -> A buffers
    conv_kernel<<<dim3(NBLK), dim3(256), 0, stream>>>(nodeB, eidx, edge_tiles, PsB, PnB,
                                                      WcB + 8192, bias_c + 128, a2, nodeA,
                                                      WsnBhi + 32768, WsnBlo + 32768,
                                                      PsA, PnA);
    // conv3 (reads A), no fused P
    conv_kernel<<<dim3(NBLK), dim3(256), 0, stream>>>(nodeA, eidx, edge_tiles, PsA, PnA,
                                                      WcB + 16384, bias_c + 256, a3, out,
                                                      nullptr, nullptr, nullptr, nullptr);
}